// Round 4
// baseline (615.187 us; speedup 1.0000x reference)
//
#include <hip/hip_runtime.h>

typedef __attribute__((ext_vector_type(8))) short bf16x8;
typedef __attribute__((ext_vector_type(4))) short bf16x4;
typedef __attribute__((ext_vector_type(4))) float f32x4;

#define NPEDS 65536
#define SEQ 12
#define HD 128
#define ED 64
#define MBLK 32
#define P1 136  // h-row pitch in elems (272 B): conflict-free b128 frag reads
#define WHH_FRAGS 128
#define WEFF_FRAGS 132  // 128 gate frags + 4 w_hp frags
#define NFRAGS (WHH_FRAGS + WEFF_FRAGS)
#define L2E 1.44269504088896340736f
#define NEG2L (-2.88539008177792681472f)
// float tail after frags: beff[512], b0eff[512], w2[1024]

__device__ __forceinline__ short f2bf(float x) {
  unsigned u = __builtin_bit_cast(unsigned, x);
  u += 0x7FFFu + ((u >> 16) & 1u);  // round-to-nearest-even
  return (short)(u >> 16);
}
__device__ __forceinline__ float exp2_(float x) {
#if __has_builtin(__builtin_amdgcn_exp2f)
  return __builtin_amdgcn_exp2f(x);
#else
  return exp2f(x);
#endif
}

// Physical elem position of logical 4-elem k-group a=k>>2 within a row
// (fragment-contiguous layout): lane (llo,lhi), K-tile kt reads 8 contiguous
// elems at kt*32 + lhi*8, giving k = kt*32 + lhi*4 + (e&3) + (e>>2)*16.
__device__ __forceinline__ int pe_grp(int a) {
  return (a >> 3) * 32 + (a & 3) * 8 + ((a >> 2) & 1) * 4;
}

// Gate rows are PRE-SCALED by log2e (2*log2e for gate g, torch order i,f,g,o)
// so the kernel can use exp2 directly: sigm(x)=rcp(1+exp2(-y)), y=x*log2e;
// tanh(g)=(2-R)/R with R=1+exp2(-yg), yg=2*log2e*g.
// wsB layout (shorts):
//  [0, 128*512):         step-0 B frags (w_hh, scaled), frag = (cc*4+g)*4+kt
//  [128*512, 256*512):   W_eff gate frags (scaled),     frag = (cc*4+g)*4+kt
//  [256*512, 260*512):   w_hp rel frags (UNscaled),     frag = kt
//  float tail fl[]: fl[0:512) beff, fl[512:1024) b0eff, fl[1024:2048) w2[n][2]
//  (all three scaled)
__global__ void prep_kernel(const float* __restrict__ w_ih,
                            const float* __restrict__ w_hh,
                            const float* __restrict__ w_se,
                            const float* __restrict__ w_hp,
                            const float* __restrict__ b_ih,
                            const float* __restrict__ b_hh,
                            const float* __restrict__ b_se,
                            const float* __restrict__ b_hp,
                            short* __restrict__ wsB, float* __restrict__ fl) {
  int t = blockIdx.x * 256 + threadIdx.x;
  if (t < WHH_FRAGS * 64) {
    int frag = t >> 6, l = t & 63;
    int cc = frag >> 4, g = (frag >> 2) & 3, kt = frag & 3;
    float fac = (g == 2) ? 2.0f * L2E : L2E;
    int n = g * HD + cc * 16 + (l & 15);
    bf16x8 v;
#pragma unroll
    for (int e = 0; e < 8; ++e) {
      int k = kt * 32 + ((l >> 4) << 2) + (e & 3) + ((e >> 2) << 4);
      v[e] = f2bf(w_hh[n * HD + k] * fac);
    }
    *(bf16x8*)(wsB + (size_t)frag * 512 + l * 8) = v;
  } else if (t < NFRAGS * 64) {
    int u = t - WHH_FRAGS * 64;
    int frag = u >> 6, l = u & 63;
    int llo = l & 15;
    int ks[8];
#pragma unroll
    for (int e = 0; e < 8; ++e)
      ks[e] = (frag & 3) * 32 + ((l >> 4) << 2) + (e & 3) + ((e >> 2) << 4);
    float acc[8];
    if (frag < 128) {
      int cc = frag >> 4, g = (frag >> 2) & 3;
      float fac = (g == 2) ? 2.0f * L2E : L2E;
      int n = g * HD + cc * 16 + llo;
#pragma unroll
      for (int e = 0; e < 8; ++e) acc[e] = w_hh[n * HD + ks[e]];
      for (int j = 0; j < ED; ++j) {
        float wij = w_ih[n * ED + j];
        float se0 = w_se[2 * j], se1 = w_se[2 * j + 1];
#pragma unroll
        for (int e = 0; e < 8; ++e)
          acc[e] += wij * (se0 * w_hp[ks[e]] + se1 * w_hp[HD + ks[e]]);
      }
#pragma unroll
      for (int e = 0; e < 8; ++e) acc[e] *= fac;
    } else {
#pragma unroll
      for (int e = 0; e < 8; ++e)
        acc[e] = (llo < 2) ? w_hp[llo * HD + ks[e]] : 0.f;
    }
    bf16x8 v;
#pragma unroll
    for (int e = 0; e < 8; ++e) v[e] = f2bf(acc[e]);
    *(bf16x8*)(wsB + (size_t)(WHH_FRAGS + frag) * 512 + l * 8) = v;
  } else if (t < NFRAGS * 64 + 512) {
    int n = t - NFRAGS * 64;
    float fac = ((n >> 7) == 2) ? 2.0f * L2E : L2E;
    float b = b_ih[n] + b_hh[n];
    float s0 = 0.f, w20 = 0.f, w21 = 0.f;
    for (int j = 0; j < ED; ++j) {
      float wij = w_ih[n * ED + j];
      s0 += wij * b_se[j];
      w20 += wij * w_se[2 * j];
      w21 += wij * w_se[2 * j + 1];
    }
    fl[n] = fac * (b + s0 + w20 * b_hp[0] + w21 * b_hp[1]);  // beff (s>=1)
    fl[512 + n] = fac * (b + s0);                            // b0eff (step 0)
    fl[1024 + 2 * n] = fac * w20;  // w2 = w_ih @ w_se (scaled)
    fl[1024 + 2 * n + 1] = fac * w21;
  }
}

__global__ __launch_bounds__(512, 4) void lstm_kernel(
    const float* __restrict__ lpr, const float* __restrict__ h0,
    const float* __restrict__ c0, const float* __restrict__ b_hp,
    const short* __restrict__ wsB, const float* __restrict__ fl,
    float* __restrict__ out) {
  __shared__ __align__(16) short hb[2][MBLK * P1];
  __shared__ float s_lpr[MBLK * 2];

  const int tid = threadIdx.x;
  const int cc = tid >> 6;  // wave id == 16-col chunk id (0..7)
  const int l = tid & 63;
  const int lhi = l >> 4;
  const int llo = l & 15;
  const int p0 = blockIdx.x * MBLK;
  const int hoff = (cc >> 1) * 32 + (llo >> 2) * 8 + (cc & 1) * 4 + (llo & 3);

  if (tid < 64) s_lpr[tid] = lpr[(size_t)p0 * 2 + tid];

  // folded bias (steps >= 1) -> registers
  float biasE[4];
#pragma unroll
  for (int g = 0; g < 4; ++g) biasE[g] = fl[g * HD + cc * 16 + llo];

  // c0 -> registers (C-tile layout, one 16-col chunk per wave, 2 M-tiles)
  float creg[2][4];
#pragma unroll
  for (int Mt = 0; Mt < 2; ++Mt)
#pragma unroll
    for (int r = 0; r < 4; ++r)
      creg[Mt][r] =
          c0[(size_t)(p0 + Mt * 16 + lhi * 4 + r) * HD + cc * 16 + llo];

  const float bhp_l = (llo < 2) ? b_hp[llo] : 0.f;

  // stage h0 -> hb[0] (pe layout): 1024 groups of 4 elems
#pragma unroll
  for (int i = 0; i < 2; ++i) {
    int grp = i * 512 + tid;
    int p = grp >> 5, a = grp & 31;
    f32x4 v = *(const f32x4*)(h0 + (size_t)(p0 + p) * HD + a * 4);
    bf16x4 s;
    s[0] = f2bf(v[0]); s[1] = f2bf(v[1]); s[2] = f2bf(v[2]); s[3] = f2bf(v[3]);
    *(bf16x4*)(&hb[0][p * P1 + pe_grp(a)]) = s;
  }
  __syncthreads();

  // 7-trans nonlinearity (gates pre-scaled by log2e / 2log2e):
  // cn = [c*Q*R + (2-R)*P] * rcp(P*Q*R);  hn = (2-T) * rcp(S*T)
  auto lstm_update = [&](f32x4 (&acc)[4][2], short* An) {
#pragma unroll
    for (int Mt = 0; Mt < 2; ++Mt)
#pragma unroll
      for (int r = 0; r < 4; ++r) {
        float yi = acc[0][Mt][r], yf = acc[1][Mt][r];
        float yg = acc[2][Mt][r], yo = acc[3][Mt][r];
        float P = 1.f + exp2_(-yf);
        float Q = 1.f + exp2_(-yi);
        float R = 1.f + exp2_(-yg);
        float QR = Q * R;
        float rD = __builtin_amdgcn_rcpf(P * QR);
        float cn = (creg[Mt][r] * QR + (2.f - R) * P) * rD;
        creg[Mt][r] = cn;
        float T = 1.f + exp2_(cn * NEG2L);
        float S = 1.f + exp2_(-yo);
        float hn = (2.f - T) * __builtin_amdgcn_rcpf(S * T);
        An[(Mt * 16 + lhi * 4 + r) * P1 + hoff] = f2bf(hn);
      }
  };

  // rel(s) for M-tile Mt = cc-6, on waves 6..7 (A-frags re-read from LDS)
  auto rel_tail = [&](const short* A, int s) {
    const short* wsR = wsB + (size_t)(WHH_FRAGS + 128) * 512;
    const int Mt = cc - 6;
    f32x4 ar = {bhp_l, bhp_l, bhp_l, bhp_l};
#pragma unroll
    for (int kt = 0; kt < 4; ++kt) {
      bf16x8 Bf = *(const bf16x8*)(wsR + (size_t)kt * 512 + l * 8);
      bf16x8 Afr =
          *(const bf16x8*)(&A[(Mt * 16 + llo) * P1 + kt * 32 + lhi * 8]);
      ar = __builtin_amdgcn_mfma_f32_16x16x32_bf16(Afr, Bf, ar, 0, 0, 0);
    }
    if (llo < 2) {
#pragma unroll
      for (int r = 0; r < 4; ++r)
        out[(size_t)s * (NPEDS * 2) +
            (size_t)(p0 + Mt * 16 + lhi * 4 + r) * 2 + llo] = ar[r];
    }
  };

  // ---- step 0: gates = h0 @ w_hh.T + lpr @ w2.T + b0eff (rank-2 fold) ----
  {
    f32x4 acc[4][2];
#pragma unroll
    for (int g = 0; g < 4; ++g) {
      int n = g * HD + cc * 16 + llo;
      float b0 = fl[512 + n];
      float w20 = fl[1024 + 2 * n];
      float w21 = fl[1024 + 2 * n + 1];
#pragma unroll
      for (int Mt = 0; Mt < 2; ++Mt)
#pragma unroll
        for (int r = 0; r < 4; ++r) {
          int row = Mt * 16 + lhi * 4 + r;
          acc[g][Mt][r] = b0 + w20 * s_lpr[row * 2] + w21 * s_lpr[row * 2 + 1];
        }
    }
#pragma unroll
    for (int kt = 0; kt < 4; ++kt) {
      bf16x8 Af[2];
#pragma unroll
      for (int Mt = 0; Mt < 2; ++Mt)
        Af[Mt] =
            *(const bf16x8*)(&hb[0][(Mt * 16 + llo) * P1 + kt * 32 + lhi * 8]);
#pragma unroll
      for (int g = 0; g < 4; ++g) {
        bf16x8 Bf = *(const bf16x8*)(wsB +
                        (size_t)((cc * 4 + g) * 4 + kt) * 512 + l * 8);
#pragma unroll
        for (int Mt = 0; Mt < 2; ++Mt)
          acc[g][Mt] = __builtin_amdgcn_mfma_f32_16x16x32_bf16(
              Af[Mt], Bf, acc[g][Mt], 0, 0, 0);
      }
    }
    lstm_update(acc, hb[1]);
    __syncthreads();
  }

  // ---- steps 1..11: gates = h @ W_eff.T + beff; rel(s-1) on waves 6..7 ----
  const short* wsW = wsB + (size_t)WHH_FRAGS * 512;
  for (int s = 1; s < SEQ; ++s) {
    const short* A = hb[s & 1];
    short* An = hb[(s + 1) & 1];
    f32x4 acc[4][2];
#pragma unroll
    for (int g = 0; g < 4; ++g) {
      f32x4 bv = {biasE[g], biasE[g], biasE[g], biasE[g]};
#pragma unroll
      for (int Mt = 0; Mt < 2; ++Mt) acc[g][Mt] = bv;
    }
#pragma unroll
    for (int kt = 0; kt < 4; ++kt) {
      bf16x8 Af[2];
#pragma unroll
      for (int Mt = 0; Mt < 2; ++Mt)
        Af[Mt] =
            *(const bf16x8*)(&A[(Mt * 16 + llo) * P1 + kt * 32 + lhi * 8]);
#pragma unroll
      for (int g = 0; g < 4; ++g) {
        bf16x8 Bf = *(const bf16x8*)(wsW +
                        (size_t)((cc * 4 + g) * 4 + kt) * 512 + l * 8);
#pragma unroll
        for (int Mt = 0; Mt < 2; ++Mt)
          acc[g][Mt] = __builtin_amdgcn_mfma_f32_16x16x32_bf16(
              Af[Mt], Bf, acc[g][Mt], 0, 0, 0);
      }
    }
    lstm_update(acc, An);
    if (cc >= 6) rel_tail(A, s - 1);
    __syncthreads();
  }

  // ---- epilogue: rel(11) from h(12) in hb[SEQ & 1] ----
  if (cc >= 6) rel_tail(hb[SEQ & 1], SEQ - 1);
}

extern "C" void kernel_launch(void* const* d_in, const int* in_sizes, int n_in,
                              void* d_out, int out_size, void* d_ws,
                              size_t ws_size, hipStream_t stream) {
  // setup_inputs order:
  // 0 last_pos (unused), 1 last_pos_rel, 2 h0, 3 c0, 4 w_ih, 5 w_hh,
  // 6 b_ih, 7 b_hh, 8 w_se, 9 b_se, 10 w_hp, 11 b_hp
  const float* lpr = (const float*)d_in[1];
  const float* h0 = (const float*)d_in[2];
  const float* c0 = (const float*)d_in[3];
  const float* w_ih = (const float*)d_in[4];
  const float* w_hh = (const float*)d_in[5];
  const float* b_ih = (const float*)d_in[6];
  const float* b_hh = (const float*)d_in[7];
  const float* w_se = (const float*)d_in[8];
  const float* b_se = (const float*)d_in[9];
  const float* w_hp = (const float*)d_in[10];
  const float* b_hp = (const float*)d_in[11];
  short* wsB = (short*)d_ws;  // frags 266240 B + float tail 8192 B = 274432 B
  float* fl = (float*)((char*)d_ws + (size_t)NFRAGS * 512 * sizeof(short));
  float* out = (float*)d_out;

  prep_kernel<<<67, 256, 0, stream>>>(w_ih, w_hh, w_se, w_hp, b_ih, b_hh,
                                      b_se, b_hp, wsB, fl);
  lstm_kernel<<<NPEDS / MBLK, 512, 0, stream>>>(lpr, h0, c0, b_hp, wsB, fl,
                                                out);
}

// Round 5
// 155.111 us; speedup vs baseline: 3.9661x; 3.9661x over previous
//
#include <hip/hip_runtime.h>

typedef __attribute__((ext_vector_type(8))) short bf16x8;
typedef __attribute__((ext_vector_type(4))) short bf16x4;
typedef __attribute__((ext_vector_type(4))) float f32x4;

#define NPEDS 65536
#define SEQ 12
#define HD 128
#define ED 64
#define MBLK 64
#define P1 136  // h-row pitch in elems (272 B, 16B-aligned rows)
#define WHH_FRAGS 128
#define WEFF_FRAGS 132  // 128 gate frags + 4 w_hp frags
#define NFRAGS (WHH_FRAGS + WEFF_FRAGS)
#define L2E 1.44269504088896340736f
#define NEG2L (-2.88539008177792681472f)
// float tail after frags: beff[512], b0eff[512], w2[1024]

__device__ __forceinline__ short f2bf(float x) {
  unsigned u = __builtin_bit_cast(unsigned, x);
  u += 0x7FFFu + ((u >> 16) & 1u);  // round-to-nearest-even
  return (short)(u >> 16);
}
__device__ __forceinline__ float exp2_(float x) {
#if __has_builtin(__builtin_amdgcn_exp2f)
  return __builtin_amdgcn_exp2f(x);
#else
  return exp2f(x);
#endif
}

// Physical elem position of logical 4-elem k-group a=k>>2 within a row
// (fragment-contiguous layout): lane (llo,lhi), K-tile kt reads 8 contiguous
// elems at kt*32 + lhi*8, giving k = kt*32 + lhi*4 + (e&3) + (e>>2)*16.
__device__ __forceinline__ int pe_grp(int a) {
  return (a >> 3) * 32 + (a & 3) * 8 + ((a >> 2) & 1) * 4;
}

// Gate rows are PRE-SCALED by log2e (2*log2e for gate g, torch order i,f,g,o)
// so the kernel can use exp2 directly: sigm(x)=rcp(1+exp2(-y)), y=x*log2e;
// tanh(g)=(2-R)/R with R=1+exp2(-yg), yg=2*log2e*g.
// wsB layout (shorts):
//  [0, 128*512):         step-0 B frags (w_hh, scaled), frag = (cc*4+g)*4+kt
//  [128*512, 256*512):   W_eff gate frags (scaled),     frag = (cc*4+g)*4+kt
//  [256*512, 260*512):   w_hp rel frags (UNscaled),     frag = kt
//  float tail fl[]: fl[0:512) beff, fl[512:1024) b0eff, fl[1024:2048) w2[n][2]
//  (all three scaled)
__global__ void prep_kernel(const float* __restrict__ w_ih,
                            const float* __restrict__ w_hh,
                            const float* __restrict__ w_se,
                            const float* __restrict__ w_hp,
                            const float* __restrict__ b_ih,
                            const float* __restrict__ b_hh,
                            const float* __restrict__ b_se,
                            const float* __restrict__ b_hp,
                            short* __restrict__ wsB, float* __restrict__ fl) {
  int t = blockIdx.x * 256 + threadIdx.x;
  if (t < WHH_FRAGS * 64) {
    int frag = t >> 6, l = t & 63;
    int cc = frag >> 4, g = (frag >> 2) & 3, kt = frag & 3;
    float fac = (g == 2) ? 2.0f * L2E : L2E;
    int n = g * HD + cc * 16 + (l & 15);
    bf16x8 v;
#pragma unroll
    for (int e = 0; e < 8; ++e) {
      int k = kt * 32 + ((l >> 4) << 2) + (e & 3) + ((e >> 2) << 4);
      v[e] = f2bf(w_hh[n * HD + k] * fac);
    }
    *(bf16x8*)(wsB + (size_t)frag * 512 + l * 8) = v;
  } else if (t < NFRAGS * 64) {
    int u = t - WHH_FRAGS * 64;
    int frag = u >> 6, l = u & 63;
    int llo = l & 15;
    int ks[8];
#pragma unroll
    for (int e = 0; e < 8; ++e)
      ks[e] = (frag & 3) * 32 + ((l >> 4) << 2) + (e & 3) + ((e >> 2) << 4);
    float acc[8];
    if (frag < 128) {
      int cc = frag >> 4, g = (frag >> 2) & 3;
      float fac = (g == 2) ? 2.0f * L2E : L2E;
      int n = g * HD + cc * 16 + llo;
#pragma unroll
      for (int e = 0; e < 8; ++e) acc[e] = w_hh[n * HD + ks[e]];
      for (int j = 0; j < ED; ++j) {
        float wij = w_ih[n * ED + j];
        float se0 = w_se[2 * j], se1 = w_se[2 * j + 1];
#pragma unroll
        for (int e = 0; e < 8; ++e)
          acc[e] += wij * (se0 * w_hp[ks[e]] + se1 * w_hp[HD + ks[e]]);
      }
#pragma unroll
      for (int e = 0; e < 8; ++e) acc[e] *= fac;
    } else {
#pragma unroll
      for (int e = 0; e < 8; ++e)
        acc[e] = (llo < 2) ? w_hp[llo * HD + ks[e]] : 0.f;
    }
    bf16x8 v;
#pragma unroll
    for (int e = 0; e < 8; ++e) v[e] = f2bf(acc[e]);
    *(bf16x8*)(wsB + (size_t)(WHH_FRAGS + frag) * 512 + l * 8) = v;
  } else if (t < NFRAGS * 64 + 512) {
    int n = t - NFRAGS * 64;
    float fac = ((n >> 7) == 2) ? 2.0f * L2E : L2E;
    float b = b_ih[n] + b_hh[n];
    float s0 = 0.f, w20 = 0.f, w21 = 0.f;
    for (int j = 0; j < ED; ++j) {
      float wij = w_ih[n * ED + j];
      s0 += wij * b_se[j];
      w20 += wij * w_se[2 * j];
      w21 += wij * w_se[2 * j + 1];
    }
    fl[n] = fac * (b + s0 + w20 * b_hp[0] + w21 * b_hp[1]);  // beff (s>=1)
    fl[512 + n] = fac * (b + s0);                            // b0eff (step 0)
    fl[1024 + 2 * n] = fac * w20;  // w2 = w_ih @ w_se (scaled)
    fl[1024 + 2 * n + 1] = fac * w21;
  }
}

__global__ __launch_bounds__(512, 2) void lstm_kernel(
    const float* __restrict__ lpr, const float* __restrict__ h0,
    const float* __restrict__ c0, const float* __restrict__ b_hp,
    const short* __restrict__ wsB, const float* __restrict__ fl,
    float* __restrict__ out) {
  __shared__ __align__(16) short hb[2][MBLK * P1];
  __shared__ float s_lpr[MBLK * 2];

  const int tid = threadIdx.x;
  const int cc = tid >> 6;  // wave id == 16-col chunk id (0..7)
  const int l = tid & 63;
  const int lhi = l >> 4;
  const int llo = l & 15;
  const int p0 = blockIdx.x * MBLK;
  const int hoff = (cc >> 1) * 32 + (llo >> 2) * 8 + (cc & 1) * 4 + (llo & 3);

  if (tid < 128) s_lpr[tid] = lpr[(size_t)p0 * 2 + tid];

  // folded bias (steps >= 1) -> registers
  float biasE[4];
#pragma unroll
  for (int g = 0; g < 4; ++g) biasE[g] = fl[g * HD + cc * 16 + llo];

  // persistent W_eff B-fragments for this wave's chunk: 16 frags, 64 VGPR.
  // Loaded once; reused by all 11 recurrence steps (no per-step L2 reads).
  const short* wsW = wsB + (size_t)WHH_FRAGS * 512;
  bf16x8 Bw[4][4];
#pragma unroll
  for (int g = 0; g < 4; ++g)
#pragma unroll
    for (int kt = 0; kt < 4; ++kt)
      Bw[g][kt] = *(const bf16x8*)(wsW +
                      (size_t)((cc * 4 + g) * 4 + kt) * 512 + l * 8);

  // c0 -> registers (C-tile layout, one 16-col chunk per wave, 4 M-tiles)
  float creg[4][4];
#pragma unroll
  for (int Mt = 0; Mt < 4; ++Mt)
#pragma unroll
    for (int r = 0; r < 4; ++r)
      creg[Mt][r] =
          c0[(size_t)(p0 + Mt * 16 + lhi * 4 + r) * HD + cc * 16 + llo];

  const float bhp_l = (llo < 2) ? b_hp[llo] : 0.f;

  // stage h0 -> hb[0] (pe layout): 2048 groups of 4 elems
#pragma unroll
  for (int i = 0; i < 4; ++i) {
    int grp = i * 512 + tid;
    int p = grp >> 5, a = grp & 31;
    f32x4 v = *(const f32x4*)(h0 + (size_t)(p0 + p) * HD + a * 4);
    bf16x4 s;
    s[0] = f2bf(v[0]); s[1] = f2bf(v[1]); s[2] = f2bf(v[2]); s[3] = f2bf(v[3]);
    *(bf16x4*)(&hb[0][p * P1 + pe_grp(a)]) = s;
  }
  __syncthreads();

  // 7-trans nonlinearity (gates pre-scaled by log2e / 2log2e):
  // cn = [c*Q*R + (2-R)*P] * rcp(P*Q*R);  hn = (2-T) * rcp(S*T)
  auto lstm_update = [&](f32x4 (&acc)[4][4], short* An) {
#pragma unroll
    for (int Mt = 0; Mt < 4; ++Mt)
#pragma unroll
      for (int r = 0; r < 4; ++r) {
        float yi = acc[0][Mt][r], yf = acc[1][Mt][r];
        float yg = acc[2][Mt][r], yo = acc[3][Mt][r];
        float P = 1.f + exp2_(-yf);
        float Q = 1.f + exp2_(-yi);
        float R = 1.f + exp2_(-yg);
        float QR = Q * R;
        float rD = __builtin_amdgcn_rcpf(P * QR);
        float cn = (creg[Mt][r] * QR + (2.f - R) * P) * rD;
        creg[Mt][r] = cn;
        float T = 1.f + exp2_(cn * NEG2L);
        float S = 1.f + exp2_(-yo);
        float hn = (2.f - T) * __builtin_amdgcn_rcpf(S * T);
        An[(Mt * 16 + lhi * 4 + r) * P1 + hoff] = f2bf(hn);
      }
  };

  // rel(s) for M-tile Mt = cc-4, on waves 4..7 (A-frags re-read from LDS)
  auto rel_tail = [&](const short* A, int s) {
    const short* wsR = wsB + (size_t)(WHH_FRAGS + 128) * 512;
    const int Mt = cc - 4;
    f32x4 ar = {bhp_l, bhp_l, bhp_l, bhp_l};
#pragma unroll
    for (int kt = 0; kt < 4; ++kt) {
      bf16x8 Bf = *(const bf16x8*)(wsR + (size_t)kt * 512 + l * 8);
      bf16x8 Afr =
          *(const bf16x8*)(&A[(Mt * 16 + llo) * P1 + kt * 32 + lhi * 8]);
      ar = __builtin_amdgcn_mfma_f32_16x16x32_bf16(Afr, Bf, ar, 0, 0, 0);
    }
    if (llo < 2) {
#pragma unroll
      for (int r = 0; r < 4; ++r)
        out[(size_t)s * (NPEDS * 2) +
            (size_t)(p0 + Mt * 16 + lhi * 4 + r) * 2 + llo] = ar[r];
    }
  };

  // ---- step 0: gates = h0 @ w_hh.T + lpr @ w2.T + b0eff (rank-2 fold) ----
  {
    f32x4 acc[4][4];
#pragma unroll
    for (int g = 0; g < 4; ++g) {
      int n = g * HD + cc * 16 + llo;
      float b0 = fl[512 + n];
      float w20 = fl[1024 + 2 * n];
      float w21 = fl[1024 + 2 * n + 1];
#pragma unroll
      for (int Mt = 0; Mt < 4; ++Mt)
#pragma unroll
        for (int r = 0; r < 4; ++r) {
          int row = Mt * 16 + lhi * 4 + r;
          acc[g][Mt][r] = b0 + w20 * s_lpr[row * 2] + w21 * s_lpr[row * 2 + 1];
        }
    }
#pragma unroll
    for (int kt = 0; kt < 4; ++kt) {
      bf16x8 Af[4];
#pragma unroll
      for (int Mt = 0; Mt < 4; ++Mt)
        Af[Mt] =
            *(const bf16x8*)(&hb[0][(Mt * 16 + llo) * P1 + kt * 32 + lhi * 8]);
#pragma unroll
      for (int g = 0; g < 4; ++g) {
        bf16x8 Bf = *(const bf16x8*)(wsB +
                        (size_t)((cc * 4 + g) * 4 + kt) * 512 + l * 8);
#pragma unroll
        for (int Mt = 0; Mt < 4; ++Mt)
          acc[g][Mt] = __builtin_amdgcn_mfma_f32_16x16x32_bf16(
              Af[Mt], Bf, acc[g][Mt], 0, 0, 0);
      }
    }
    lstm_update(acc, hb[1]);
    __syncthreads();
  }

  // ---- steps 1..11: gates = h @ W_eff.T + beff (B in regs) ----
  for (int s = 1; s < SEQ; ++s) {
    const short* A = hb[s & 1];
    short* An = hb[(s + 1) & 1];
    f32x4 acc[4][4];
#pragma unroll
    for (int g = 0; g < 4; ++g) {
      f32x4 bv = {biasE[g], biasE[g], biasE[g], biasE[g]};
#pragma unroll
      for (int Mt = 0; Mt < 4; ++Mt) acc[g][Mt] = bv;
    }
#pragma unroll
    for (int kt = 0; kt < 4; ++kt) {
      bf16x8 Af[4];
#pragma unroll
      for (int Mt = 0; Mt < 4; ++Mt)
        Af[Mt] =
            *(const bf16x8*)(&A[(Mt * 16 + llo) * P1 + kt * 32 + lhi * 8]);
#pragma unroll
      for (int g = 0; g < 4; ++g)
#pragma unroll
        for (int Mt = 0; Mt < 4; ++Mt)
          acc[g][Mt] = __builtin_amdgcn_mfma_f32_16x16x32_bf16(
              Af[Mt], Bw[g][kt], acc[g][Mt], 0, 0, 0);
    }
    lstm_update(acc, An);
    if (cc >= 4) rel_tail(A, s - 1);
    __syncthreads();
  }

  // ---- epilogue: rel(11) from h(12) in hb[SEQ & 1] ----
  if (cc >= 4) rel_tail(hb[SEQ & 1], SEQ - 1);
}

extern "C" void kernel_launch(void* const* d_in, const int* in_sizes, int n_in,
                              void* d_out, int out_size, void* d_ws,
                              size_t ws_size, hipStream_t stream) {
  // setup_inputs order:
  // 0 last_pos (unused), 1 last_pos_rel, 2 h0, 3 c0, 4 w_ih, 5 w_hh,
  // 6 b_ih, 7 b_hh, 8 w_se, 9 b_se, 10 w_hp, 11 b_hp
  const float* lpr = (const float*)d_in[1];
  const float* h0 = (const float*)d_in[2];
  const float* c0 = (const float*)d_in[3];
  const float* w_ih = (const float*)d_in[4];
  const float* w_hh = (const float*)d_in[5];
  const float* b_ih = (const float*)d_in[6];
  const float* b_hh = (const float*)d_in[7];
  const float* w_se = (const float*)d_in[8];
  const float* b_se = (const float*)d_in[9];
  const float* w_hp = (const float*)d_in[10];
  const float* b_hp = (const float*)d_in[11];
  short* wsB = (short*)d_ws;  // frags 266240 B + float tail 8192 B = 274432 B
  float* fl = (float*)((char*)d_ws + (size_t)NFRAGS * 512 * sizeof(short));
  float* out = (float*)d_out;

  prep_kernel<<<67, 256, 0, stream>>>(w_ih, w_hh, w_se, w_hp, b_ih, b_hh,
                                      b_se, b_hp, wsB, fl);
  lstm_kernel<<<NPEDS / MBLK, 512, 0, stream>>>(lpr, h0, c0, b_hp, wsB, fl,
                                                out);
}